// Round 3
// baseline (442.066 us; speedup 1.0000x reference)
//
#include <hip/hip_runtime.h>
#include <cstdint>

#define NPIX  1024
#define NH    992
#define NEDGE 1984
#define NSORT 2048
#define NGRP  31
#define HFS   4300
#define POOLN (NPIX + 2*HFS)   // 9624 u32 entries

typedef unsigned long long u64;
typedef unsigned int u32;

// ---- workspace layout (bytes) ----
#define WS_SEG   0                        // u16 [128][1024]   = 262144
#define WS_KS    262144                   // u32 [256][2048]   = 2097152
#define WS_Q     2359296                  // u32 [256][1024]   = 1048576
#define WS_QN    3407872                  // int [256]         = 1024

// root_ pack (labeled live sets only; 0 == dead/unlabeled):
// sL[0,11) | off[11,25) | len[25,36) | cap[36,47)
static __device__ __forceinline__ u64 packRoot(int sL,int off,int len,int cap){
    return (u64)(u32)(sL & 0x7FF) | ((u64)(u32)(off & 0x3FFF) << 11) |
           ((u64)(u32)(len & 0x7FF) << 25) | ((u64)(u32)(cap & 0x7FF) << 36);
}
#define R_SL(R)  ((int)((R) & 0x7FF))
#define R_OFF(R) ((int)(((R)>>11) & 0x3FFF))
#define R_LEN(R) ((int)(((R)>>25) & 0x7FF))
#define R_CAP(R) ((int)(((R)>>36) & 0x7FF))

static __device__ __forceinline__ int rdl(int v, int l){ return __builtin_amdgcn_readlane(v, l); }

static __device__ __forceinline__ u64 sxor64(u64 v, int m){
    u32 lo = (u32)__shfl_xor((int)(v & 0xFFFFFFFFull), m, 64);
    u32 hi = (u32)__shfl_xor((int)(v >> 32), m, 64);
    return ((u64)hi << 32) | lo;
}

// edge id -> endpoints (reference order: 992 horizontal then 992 vertical)
static __device__ __forceinline__ void edgeAB(int e, int &a, int &b){
    if (e < NH) { int r = (int)((unsigned)e / 31u); a = e + r; b = a + 1; }
    else        { a = e - NH; b = a + 32; }
}

static __device__ __forceinline__ int winBase(int wslot){
    int bb = wslot >> 6;
    int win = wslot & 63;
    int wy = win >> 3, wx = win & 7;
    return bb * 65536 + (wy * 32) * 256 + wx * 32;
}

// in-register compare-exchange: x at lower global index
#define CE(x, y, up) { u64 _a=(x), _b=(y); bool _lt=(_a<_b); \
    u64 _mn=_lt?_a:_b, _mx=_lt?_b:_a; (x)=(up)?_mn:_mx; (y)=(up)?_mx:_mn; }
// cross-lane compare-exchange via shfl_xor
#define CEX(x, xm, keepmin) { u64 _p=sxor64((x),(xm)); bool _lt=((x)<_p); \
    u64 _mn=_lt?(x):_p, _mx=_lt?_p:(x); (x)=(keepmin)?_mn:_mx; }

static __device__ __forceinline__ int wredi(int v){
    #pragma unroll
    for (int o = 32; o > 0; o >>= 1) v += __shfl_xor(v, o, 64);
    return v;
}
static __device__ __forceinline__ float wredf(float v){
    #pragma unroll
    for (int o = 32; o > 0; o >>= 1) v += __shfl_xor(v, o, 64);
    return v;
}

// ================= K1: dilate + run-based CCL -> seg =================
__global__ __launch_bounds__(128) void seg_kernel(
    const float* __restrict__ target,
    unsigned short* __restrict__ segW)
{
    const int tid  = threadIdx.x;
    const int lane = tid & 63;
    const int wv   = tid >> 6;
    const int bid  = blockIdx.x;          // 0..127 = window slot
    const int base = winBase(bid);

    __shared__ u32   rowmaskL[32];
    __shared__ u32   fgL[32];
    __shared__ unsigned short baseL[33];
    __shared__ u32   runPar[512];
    __shared__ unsigned short labIdRun[512];
    __shared__ int   flags[2];

    // load target zero-mask via ballot
    for (int j = 0; j < 8; ++j) {
        int i = tid + 128 * j;
        int r = i >> 5, c = i & 31;
        float tv = target[base + r * 256 + c];
        u64 zb = __ballot(tv == 0.0f);
        if (lane == 0) {
            int rr = 4 * j + 2 * wv;
            rowmaskL[rr]     = (u32)zb;
            rowmaskL[rr + 1] = (u32)(zb >> 32);
        }
    }
    if (tid == 0) flags[1] = 0;
    for (int x = tid; x < 512; x += 128) runPar[x] = (u32)x;
    __syncthreads();

    // dilate 5x in wave0 registers (lane r holds row-r mask)
    if (tid < 32) {
        u32 m = rowmaskL[tid];
        #pragma unroll
        for (int it = 0; it < 5; ++it) {
            u32 um = __shfl(m, (tid == 0) ? 0 : tid - 1, 64);
            if (tid == 0) um = 0;
            u32 dm = __shfl(m, (tid == 31) ? 31 : tid + 1, 64);
            if (tid == 31) dm = 0;
            m = m | (m << 1) | (m >> 1) | um | dm;
        }
        u32 f = ~m;
        fgL[tid] = f;
        int ns = __popc(f & ~(f << 1));
        int x = ns;
        #pragma unroll
        for (int off = 1; off < 32; off <<= 1) {
            int y = __shfl(x, (tid >= off) ? tid - off : 0, 64);
            if (tid >= off) x += y;
        }
        baseL[tid] = (unsigned short)(x - ns);
        if (tid == 31) baseL[32] = (unsigned short)x;
    }
    __syncthreads();
    const int nRuns = (int)baseL[32];

    // CCL (8-conn) as union-find over row runs
    for (;;) {
        if (tid == 0) flags[0] = 0;
        __syncthreads();
        bool chg = false;
        for (int j = 0; j < 8; ++j) {
            int i = tid + 128 * j;
            int r = i >> 5, c = i & 31;
            if (r == 0) continue;
            u32 fr = fgL[r];
            if (!((fr >> c) & 1u)) continue;
            u32 fu = fgL[r - 1];
            u32 nb = fu & (u32)((7ull << c) >> 1);
            if (!nb) continue;
            u32 Sr = fr & ~(fr << 1);
            int a = (int)baseL[r] + __popc(Sr & ((2u << c) - 1u)) - 1;
            for (;;) { int p = (int)runPar[a]; if (p == a) break; a = p; }
            u32 Su = fu & ~(fu << 1);
            int bu = (int)baseL[r - 1];
            while (nb) {
                int cc = __ffs((int)nb) - 1; nb &= nb - 1;
                int b = bu + __popc(Su & ((2u << cc) - 1u)) - 1;
                for (;;) { int p = (int)runPar[b]; if (p == b) break; b = p; }
                if (a != b) {
                    int mnr = a < b ? a : b;
                    int mxr = a ^ b ^ mnr;
                    atomicMin(&runPar[mxr], (u32)mnr);
                    chg = true;
                    a = mnr;
                }
            }
        }
        if (chg) flags[0] = 1;
        __syncthreads();
        if (!flags[0]) break;
        for (int x = tid; x < nRuns; x += 128) {
            u32 p = runPar[x];
            runPar[x] = runPar[p];
        }
        __syncthreads();
    }

    for (int x = tid; x < nRuns; x += 128)
        if ((int)runPar[x] == x) labIdRun[x] = (unsigned short)atomicAdd(&flags[1], 1);
    __syncthreads();

    unsigned short* segG = segW + bid * NPIX;
    for (int j = 0; j < 8; ++j) {
        int i = tid + 128 * j;
        int r = i >> 5, c = i & 31;
        u32 fr = fgL[r];
        unsigned short s = 0;
        if ((fr >> c) & 1u) {
            u32 Sr = fr & ~(fr << 1);
            int x = (int)baseL[r] + __popc(Sr & ((2u << c) - 1u)) - 1;
            for (;;) { int p = (int)runPar[x]; if (p == x) break; x = p; }
            s = (unsigned short)((int)labIdRun[x] + 1);
        }
        segG[i] = s;
    }
}

// ================= K2: per (window,phase) key sort =================
__global__ __launch_bounds__(64) void sort_kernel(
    const float* __restrict__ pred,
    const float* __restrict__ target,
    u32* __restrict__ KsW)
{
    const int lane = threadIdx.x;
    const int bid  = blockIdx.x;          // 0..255
    const int ph   = bid & 1;
    const int base = winBase(bid >> 1);

    __shared__ float predL[NPIX];
    __shared__ float costs[NEDGE];
    __shared__ unsigned char tgtL[NPIX];
    __shared__ unsigned char gtcL[NEDGE];

    for (int i = lane; i < NPIX; i += 64) {
        int r = i >> 5, c = i & 31;
        predL[i] = pred[base + r * 256 + c];
        tgtL[i]  = (unsigned char)target[base + r * 256 + c];
    }
    __builtin_amdgcn_wave_barrier();
    for (int e = lane; e < NEDGE; e += 64) {
        int a, b2; edgeAB(e, a, b2);
        costs[e] = predL[a] + predL[b2];
        gtcL[e]  = (unsigned char)(tgtL[a] + tgtL[b2]);
    }
    __builtin_amdgcn_wave_barrier();

    // register-resident bitonic sort of 2048 u64 keys
    u64 sk[32];
    #pragma unroll
    for (int r = 0; r < 32; ++r) {
        int e = lane * 32 + r;
        u64 kv = ~0ULL;
        if (e < NEDGE) {
            float cv = costs[e];
            int g = gtcL[e];
            if (ph == 0) { if (g > 20) cv = 20.0f; }
            else         { if (g < 10) cv = 0.0f; }
            kv = (((u64)(~__float_as_uint(cv))) << 32) | (u32)e;
        }
        sk[r] = kv;
    }
    #pragma unroll
    for (int kk2 = 2; kk2 <= 32; kk2 <<= 1) {
        #pragma unroll
        for (int j = kk2 >> 1; j > 0; j >>= 1) {
            #pragma unroll
            for (int r = 0; r < 32; ++r) {
                if ((r & j) == 0) {
                    bool up = (kk2 == 32) ? ((lane & 1) == 0) : ((r & kk2) == 0);
                    CE(sk[r], sk[r | j], up);
                }
            }
        }
    }
    #pragma unroll
    for (int kk2 = 64; kk2 <= 2048; kk2 <<= 1) {
        const bool up = ((lane & (kk2 >> 5)) == 0);
        #pragma unroll
        for (int j = kk2 >> 1; j >= 32; j >>= 1) {
            const int xm = j >> 5;
            const bool keepmin = (((lane & xm) == 0) == up);
            #pragma unroll
            for (int r = 0; r < 32; ++r) { CEX(sk[r], xm, keepmin); }
        }
        #pragma unroll
        for (int j = 16; j > 0; j >>= 1) {
            #pragma unroll
            for (int r = 0; r < 32; ++r) {
                if ((r & j) == 0) { CE(sk[r], sk[r | j], up); }
            }
        }
    }
    u32* KsG = KsW + (size_t)bid * NSORT;
    #pragma unroll
    for (int r = 0; r < 32; r += 4) {
        uint4 v4;
        v4.x = (u32)sk[r]; v4.y = (u32)sk[r+1]; v4.z = (u32)sk[r+2]; v4.w = (u32)sk[r+3];
        *(uint4*)&KsG[lane * 32 + r] = v4;
    }
}

// ================= K3: claim-batched Kruskal drain -> Q,qn =================
__global__ __launch_bounds__(64) void drain_kernel(
    const u32* __restrict__ KsW,
    const unsigned short* __restrict__ segW,
    u32* __restrict__ QW,
    int* __restrict__ qnW)
{
    const int lane = threadIdx.x;
    const int bid  = blockIdx.x;          // 0..255
    const unsigned short* segG = segW + (bid >> 1) * NPIX;
    const u32* KsG = KsW + (size_t)bid * NSORT;

    __shared__ short par_[NPIX];          // parent[9:0] | labeledStatic<<15
    __shared__ u32   claim_[NPIX];
    __shared__ u32   Q_[NPIX];

    for (int i = lane; i < NPIX; i += 64) {
        unsigned short s2 = segG[i];
        par_[i] = (short)(i | (s2 ? 0x8000 : 0));
        claim_[i] = ~0u;
    }
    __builtin_amdgcn_wave_barrier();

    int qn = 0;
    u32 rnd = 1;
    const u64 ltm = (1ull << lane) - 1;
    int curE = (int)KsG[lane];                 // group-0 prefetch (global, L2)
    for (int g2 = 0; g2 < NGRP; ++g2) {
        int nextE = (g2 + 1 < NGRP) ? (int)KsG[(g2 + 1) * 64 + lane] : 0;
        const int myE = curE;
        int ea, eb2; edgeAB(myE, ea, eb2);
        int ra = ea, rb = eb2;
        int laA, laB;
        for (;;) {
            int va = (int)(unsigned short)par_[ra];
            int vb = (int)(unsigned short)par_[rb];
            int pa = va & 0x3FF, pb = vb & 0x3FF;
            bool fa = (pa != ra), fb = (pb != rb);
            if (!fa && !fb) { laA = va >> 15; laB = vb >> 15; break; }
            int ga = (int)(unsigned short)par_[pa];
            int gb = (int)(unsigned short)par_[pb];
            if (fa) { par_[ra] = (short)ga; ra = ga & 0x3FF; }
            if (fb) { par_[rb] = (short)gb; rb = gb & 0x3FF; }
        }
        bool alive = (ra != rb);

        for (;;) {
            if (!__ballot(alive)) break;
            const bool av = alive;
            const u32 tag = ((0x03FFFFFFu - rnd) << 6) | (u32)lane;
            ++rnd;
            int mn = ra < rb ? ra : rb;
            int mx = ra < rb ? rb : ra;
            int winner = (laA == laB) ? mn : (laA ? ra : rb);
            int loser  = (laA == laB) ? mx : (laA ? rb : ra);
            bool wgt = (laA & laB) != 0;
            if (av)        atomicMin(&claim_[loser],  tag);
            if (av && wgt) atomicMin(&claim_[winner], tag);
            bool sel = false;
            if (av) {
                u32 cl = claim_[loser];
                u32 cw = wgt ? claim_[winner] : tag;
                sel = (cl == tag) && (cw == tag);
            }
            u64 wm = __ballot(sel && wgt);
            if (sel && wgt) Q_[qn + __popcll(wm & ltm)] =
                (u32)myE | ((u32)mn << 11) | ((u32)mx << 21);
            qn += (int)__popcll(wm);
            if (sel) par_[loser] = (short)winner;
            if (av) {
                for (;;) {
                    int va = (int)(unsigned short)par_[ra];
                    int vb = (int)(unsigned short)par_[rb];
                    int pa = va & 0x3FF, pb = vb & 0x3FF;
                    bool fa = (pa != ra), fb = (pb != rb);
                    if (!fa && !fb) { laA = va >> 15; laB = vb >> 15; break; }
                    int ga = (int)(unsigned short)par_[pa];
                    int gb = (int)(unsigned short)par_[pb];
                    if (fa) { par_[ra] = (short)ga; ra = ga & 0x3FF; }
                    if (fb) { par_[rb] = (short)gb; rb = gb & 0x3FF; }
                }
                alive = !sel && (ra != rb);
            }
        }
        curE = nextE;
        __builtin_amdgcn_wave_barrier();
    }

    u32* QG = QW + (size_t)bid * NPIX;
    for (int q = lane; q < qn; q += 64) QG[q] = Q_[q];
    if (lane == 0) qnW[bid] = qn;
}

// ================= K4: replay + epilogue =================
__global__ __launch_bounds__(64) void replay_kernel(
    const float* __restrict__ pred,
    const float* __restrict__ target,
    const unsigned short* __restrict__ segW,
    const u32* __restrict__ QW,
    const int* __restrict__ qnW,
    const float* __restrict__ lr_p,
    const float* __restrict__ lrp_p,
    float* __restrict__ out)
{
    const int lane = threadIdx.x;
    const int bid  = blockIdx.x;          // 0..255
    const int ph   = bid & 1;
    const int base = winBase(bid >> 1);
    const unsigned short* segG = segW + (bid >> 1) * NPIX;
    const u32* QG = QW + (size_t)bid * NPIX;
    const int qn = qnW[bid];

    __shared__ u64   root_[NPIX];
    __shared__ u32   pool_[POOLN];
    __shared__ u32   Q_[NPIX];
    __shared__ float Qw_[NPIX];
    __shared__ short H_[NPIX + 1];
    __shared__ float predL[NPIX];
    __shared__ unsigned char tgtL[NPIX];
    __shared__ unsigned char gtcL[NEDGE];

    for (int i = lane; i < NPIX; i += 64) {
        int r = i >> 5, c = i & 31;
        predL[i] = pred[base + r * 256 + c];
        tgtL[i]  = (unsigned char)target[base + r * 256 + c];
        unsigned short s2 = segG[i];
        if (s2) {
            root_[i] = packRoot(1, i, 1, 1);
            pool_[i] = ((u32)s2 << 16) | 1u;
        } else {
            root_[i] = 0;
        }
        H_[i] = 0;
    }
    if (lane == 0) H_[NPIX] = 0;
    for (int q = lane; q < qn; q += 64) Q_[q] = QG[q];
    __builtin_amdgcn_wave_barrier();
    for (int e = lane; e < NEDGE; e += 64) {
        int a, b2; edgeAB(e, a, b2);
        gtcL[e] = (unsigned char)(tgtL[a] + tgtL[b2]);
    }
    __builtin_amdgcn_wave_barrier();

    const u64 ltm = (1ull << lane) - 1;
    u32 bump = NPIX;
    u32 halfEnd = NPIX + HFS;
    int curHalf = 0;

    auto do_gc = [&]() {
        u32 tgt = (curHalf == 0) ? (u32)(NPIX + HFS) : (u32)NPIX;
        u32 nb = tgt;
        for (int c = 0; c < 16; ++c) {
            int i0 = c * 64 + lane;
            bool live = (root_[i0] != 0);
            u64 rbm = __ballot(live);
            while (rbm) {
                int j = __ffsll(rbm) - 1; rbm &= rbm - 1;
                int r = c * 64 + j;
                u64 R = root_[r];
                int len = R_LEN(R);
                int off = R_OFF(R);
                for (int t = lane; t < len; t += 64) {
                    u32 v2 = pool_[off + t];
                    pool_[nb + t] = v2;
                }
                __builtin_amdgcn_wave_barrier();
                if (lane == 0) root_[r] = packRoot(R_SL(R), (int)nb, len, len);
                nb += (u32)len;
            }
        }
        bump = nb;
        halfEnd = tgt + HFS;
        curHalf ^= 1;
    };

    for (int q = 0; q < qn; ++q) {
        u32 rec = Q_[q];
        int A  = (int)((rec >> 11) & 0x3FF);
        int B  = (int)((rec >> 21) & 0x3FF);
        int winner = A;
        int dead   = B;
        u64 RA = root_[A], RB = root_[B];
        int sLa = R_SL(RA), sLb = R_SL(RB);
        int lenA = R_LEN(RA), lenB = R_LEN(RB);
        if (bump + (u32)(lenA + lenB + 8) > halfEnd) {
            do_gc();
            RA = root_[A]; RB = root_[B];
            lenA = R_LEN(RA); lenB = R_LEN(RB);
        }
        int offA = R_OFF(RA), capA = R_CAP(RA);
        int offB = R_OFF(RB), capB = R_CAP(RB);
        int offS, lenS, offL, lenL, capL;
        if (lenA <= lenB) { offS = offA; lenS = lenA; offL = offB; lenL = lenB; capL = capB; }
        else              { offS = offB; lenS = lenB; offL = offA; lenL = lenA; capL = capA; }
        int same = 0, dOff, dLen, dCap;

        if (lenS + lenL <= 64) {
            u32 eL = (lane < lenL) ? pool_[offL + lane] : 0u;
            u32 eS = (lane < lenS) ? pool_[offS + lane] : 0u;
            dLen = lenL;
            for (int t = 0; t < lenS; ++t) {
                u32 xs = (u32)rdl((int)eS, t);
                bool match = (lane < lenL) && ((eL >> 16) == (xs >> 16));
                u64 mb = __ballot(match);
                if (mb) {
                    int ml = __ffsll(mb) - 1;
                    same += (int)(xs & 0xFFFF) * ((int)rdl((int)eL, ml) & 0xFFFF);
                    if (match) eL += (xs & 0xFFFF);
                } else {
                    if (lane == dLen) eL = xs;
                    dLen++;
                }
            }
            if (dLen <= capL) { dOff = offL; dCap = capL; }
            else { dOff = (int)bump; dCap = (dLen + 3) & ~3; bump += (u32)dCap; }
            if (lane < dLen) pool_[dOff + lane] = eL;
        } else {
            dOff = (int)bump;
            dCap = (lenL + lenS + 4) & ~3; bump += (u32)dCap;
            for (int j = lane; j < lenS; j += 64) {
                u32 es = pool_[offS + j];
                H_[es >> 16] = (short)(es & 0xFFFF);
            }
            __builtin_amdgcn_wave_barrier();
            int sp = 0;
            for (int j = lane; j < lenL; j += 64) {
                u32 el = pool_[offL + j];
                int h = (int)H_[el >> 16];
                sp += h * (int)(el & 0xFFFF);
                pool_[dOff + j] = el + (u32)h;
                if (h) H_[el >> 16] = 0;
            }
            same = wredi(sp);
            __builtin_amdgcn_wave_barrier();
            int baseU = 0;
            for (int j0 = 0; j0 < lenS; j0 += 64) {
                int j = j0 + lane;
                bool un = false; u32 es = 0;
                if (j < lenS) { es = pool_[offS + j]; un = (H_[es >> 16] != 0); }
                u64 ub = __ballot(un);
                if (un) {
                    int pos = __popcll(ub & ltm);
                    pool_[dOff + lenL + baseU + pos] = es;
                    H_[es >> 16] = 0;
                }
                baseU += __popcll(ub);
            }
            dLen = lenL + baseU;
        }
        if (lane == 0) {
            Qw_[q] = (float)(ph ? same : (sLa * sLb - same));
            root_[winner] = packRoot(sLa + sLb, dOff, dLen, dCap);
            root_[dead]   = 0;
        }
        __builtin_amdgcn_wave_barrier();
    }

    float s_loc = 0.0f;
    for (int q = lane; q < qn; q += 64) s_loc += Qw_[q];
    const float sn = wredf(s_loc);

    const float scale = ph ? lrp_p[0] : lr_p[0];
    float acc = 0.0f;
    for (int q = lane; q < qn; q += 64) {
        float wv2 = Qw_[q];
        if (wv2 == 0.0f) continue;
        if (sn > 0.0f) wv2 /= sn;
        int me = (int)(Q_[q] & 0x7FF);
        int g = gtcL[me];
        bool zero = ph ? (g < 20) : (g >= 10);
        if (zero) continue;
        int a2, b2; edgeAB(me, a2, b2);
        float pa = predL[a2], pb = predL[b2];
        float fa2, fb2;
        if (ph == 0) { fa2 = pa * pa; fb2 = pb * pb; }
        else { float qa = 20.0f - pa, qb = 20.0f - pb; fa2 = qa * qa; fb2 = qb * qb; }
        acc += scale * wv2 * (fa2 + fb2);
    }
    acc = wredf(acc);
    if (lane == 0) atomicAdd(out, acc);
}

__global__ void zero_out_kernel(float* o)
{
    if (threadIdx.x == 0 && blockIdx.x == 0) o[0] = 0.0f;
}

extern "C" void kernel_launch(void* const* d_in, const int* in_sizes, int n_in,
                              void* d_out, int out_size, void* d_ws, size_t ws_size,
                              hipStream_t stream)
{
    const float* pred   = (const float*)d_in[0];
    const float* target = (const float*)d_in[1];
    const float* lr     = (const float*)d_in[2];
    const float* lrp    = (const float*)d_in[3];
    float* out = (float*)d_out;

    char* ws = (char*)d_ws;
    unsigned short* segW = (unsigned short*)(ws + WS_SEG);
    u32* KsW = (u32*)(ws + WS_KS);
    u32* QW  = (u32*)(ws + WS_Q);
    int* qnW = (int*)(ws + WS_QN);

    zero_out_kernel<<<1, 64, 0, stream>>>(out);
    seg_kernel<<<128, 128, 0, stream>>>(target, segW);
    sort_kernel<<<256, 64, 0, stream>>>(pred, target, KsW);
    drain_kernel<<<256, 64, 0, stream>>>(KsW, segW, QW, qnW);
    replay_kernel<<<256, 64, 0, stream>>>(pred, target, segW, QW, qnW, lr, lrp, out);
}

// Round 4
// 337.182 us; speedup vs baseline: 1.3111x; 1.3111x over previous
//
#include <hip/hip_runtime.h>
#include <cstdint>

#define NPIX  1024
#define NH    992
#define NEDGE 1984
#define NSORT 2048
#define NGRP  31
#define HFS   4300
#define POOLN (NPIX + 2*HFS)   // 9624 u32 entries per phase

typedef unsigned long long u64;
typedef unsigned int u32;

// ---- root_ encoding ----
// 0 == dead/unlabeled.
// type = bits[62,64): 0 = pool-backed, 1 = inline x1, 2 = inline x2.
// pool-backed: sL[0,11) | off[11,25) | len[25,36) | cap[36,47)
// inline: entry k at bits[26k, 26k+26), entry = lab<<16 | cnt (lab<=1023, cnt<=1024)
static __device__ __forceinline__ u64 packRoot(int sL,int off,int len,int cap){
    return (u64)(u32)(sL & 0x7FF) | ((u64)(u32)(off & 0x3FFF) << 11) |
           ((u64)(u32)(len & 0x7FF) << 25) | ((u64)(u32)(cap & 0x7FF) << 36);
}
#define R_SL(R)  ((int)((R) & 0x7FF))
#define R_OFF(R) ((int)(((R)>>11) & 0x3FFF))
#define R_LEN(R) ((int)(((R)>>25) & 0x7FF))
#define R_CAP(R) ((int)(((R)>>36) & 0x7FF))
#define EMASK 0x3FFFFFFu

static __device__ __forceinline__ int rdl(int v, int l){ return __builtin_amdgcn_readlane(v, l); }

static __device__ __forceinline__ u64 sxor64(u64 v, int m){
    u32 lo = (u32)__shfl_xor((int)(v & 0xFFFFFFFFull), m, 64);
    u32 hi = (u32)__shfl_xor((int)(v >> 32), m, 64);
    return ((u64)hi << 32) | lo;
}

// edge id -> endpoints (reference order: 992 horizontal then 992 vertical)
static __device__ __forceinline__ void edgeAB(int e, int &a, int &b){
    if (e < NH) { int r = (int)((unsigned)e / 31u); a = e + r; b = a + 1; }
    else        { a = e - NH; b = a + 32; }
}

// in-register compare-exchange: x at lower global index
#define CE(x, y, up) { u64 _a=(x), _b=(y); bool _lt=(_a<_b); \
    u64 _mn=_lt?_a:_b, _mx=_lt?_b:_a; (x)=(up)?_mn:_mx; (y)=(up)?_mx:_mn; }
// cross-lane compare-exchange via shfl_xor
#define CEX(x, xm, keepmin) { u64 _p=sxor64((x),(xm)); bool _lt=((x)<_p); \
    u64 _mn=_lt?(x):_p, _mx=_lt?_p:(x); (x)=(keepmin)?_mn:_mx; }

static __device__ __forceinline__ int wredi(int v){
    #pragma unroll
    for (int o = 32; o > 0; o >>= 1) v += __shfl_xor(v, o, 64);
    return v;
}
static __device__ __forceinline__ float wredf(float v){
    #pragma unroll
    for (int o = 32; o > 0; o >>= 1) v += __shfl_xor(v, o, 64);
    return v;
}

__global__ __launch_bounds__(128) void malis_kernel(
    const float* __restrict__ pred,
    const float* __restrict__ target,
    const float* __restrict__ lr_p,
    const float* __restrict__ lrp_p,
    float* __restrict__ out)
{
    const int tid  = threadIdx.x;
    const int lane = tid & 63;
    const int wv   = tid >> 6;        // wave 0: negative pass, wave 1: positive pass
    const int bid  = blockIdx.x;
    const int bb   = bid >> 6;
    const int win  = bid & 63;
    const int wy   = win >> 3, wx = win & 7;
    const int base = bb * 65536 + (wy * 32) * 256 + wx * 32;

    // ---- LDS (~148 KB; 1 block/CU) ----
    __shared__ __align__(16) u32 Ks[2][NSORT]; // sorted edge indices
    __shared__ u64   root[2][NPIX];
    __shared__ float predL[NPIX];
    __shared__ float costs[NEDGE];
    __shared__ u32   poolS[2][POOLN];       // label-count arrays {lab<<16|cnt}
    __shared__ u32   Q[2][NPIX];            // weighted-merge records {e,ra,rb}
    __shared__ float Qw[2][NPIX];           // weights (claim array during drain)
    __shared__ short seg[NPIX];
    __shared__ short par[2][NPIX];          // parent[9:0] | labeledStatic<<15
    __shared__ short H[2][NPIX + 1];        // slow-path histogram
    __shared__ unsigned char tgtL[NPIX];
    __shared__ unsigned char gtcL[NEDGE];
    __shared__ u32   rowmaskL[32];
    __shared__ u32   fgL[32];
    __shared__ unsigned short baseL[33];
    __shared__ int   flags[2];

    // early scratch overlaid on poolS (dead until UF init)
    u32* runPar = (u32*)poolS;                                  // 512 u32
    unsigned short* labIdRun = (unsigned short*)(runPar + 512); // 512 u16

    // ---- load window; build (target==0) row bitmasks via ballot ----
    for (int j = 0; j < 8; ++j) {
        int i = tid + 128 * j;
        int r = i >> 5, c = i & 31;
        float pv = pred[base + r * 256 + c];
        float tv = target[base + r * 256 + c];
        predL[i] = pv;
        tgtL[i]  = (unsigned char)tv;
        u64 zb = __ballot(tv == 0.0f);
        if (lane == 0) {
            int rr = 4 * j + 2 * wv;
            rowmaskL[rr]     = (u32)zb;
            rowmaskL[rr + 1] = (u32)(zb >> 32);
        }
    }
    if (tid == 0) flags[1] = 0;
    for (int x = tid; x < 512; x += 128) runPar[x] = (u32)x;
    __syncthreads();

    // ---- dilate 5x in wave0 registers (lane r holds row-r mask) ----
    if (tid < 32) {
        u32 m = rowmaskL[tid];
        #pragma unroll
        for (int it = 0; it < 5; ++it) {
            u32 um = __shfl(m, (tid == 0) ? 0 : tid - 1, 64);
            if (tid == 0) um = 0;
            u32 dm = __shfl(m, (tid == 31) ? 31 : tid + 1, 64);
            if (tid == 31) dm = 0;
            m = m | (m << 1) | (m >> 1) | um | dm;
        }
        u32 f = ~m;
        fgL[tid] = f;
        int ns = __popc(f & ~(f << 1));
        int x = ns;
        #pragma unroll
        for (int off = 1; off < 32; off <<= 1) {
            int y = __shfl(x, (tid >= off) ? tid - off : 0, 64);
            if (tid >= off) x += y;
        }
        baseL[tid] = (unsigned short)(x - ns);
        if (tid == 31) baseL[32] = (unsigned short)x;
    }
    __syncthreads();
    const int nRuns = (int)baseL[32];

    // ---- CCL (8-conn) as union-find over row runs ----
    for (;;) {
        if (tid == 0) flags[0] = 0;
        __syncthreads();
        bool chg = false;
        for (int j = 0; j < 8; ++j) {
            int i = tid + 128 * j;
            int r = i >> 5, c = i & 31;
            if (r == 0) continue;
            u32 fr = fgL[r];
            if (!((fr >> c) & 1u)) continue;
            u32 fu = fgL[r - 1];
            u32 nb = fu & (u32)((7ull << c) >> 1);
            if (!nb) continue;
            u32 Sr = fr & ~(fr << 1);
            int a = (int)baseL[r] + __popc(Sr & ((2u << c) - 1u)) - 1;
            for (;;) { int p = (int)runPar[a]; if (p == a) break; a = p; }
            u32 Su = fu & ~(fu << 1);
            int bu = (int)baseL[r - 1];
            while (nb) {
                int cc = __ffs((int)nb) - 1; nb &= nb - 1;
                int b = bu + __popc(Su & ((2u << cc) - 1u)) - 1;
                for (;;) { int p = (int)runPar[b]; if (p == b) break; b = p; }
                if (a != b) {
                    int mnr = a < b ? a : b;
                    int mxr = a ^ b ^ mnr;
                    atomicMin(&runPar[mxr], (u32)mnr);
                    chg = true;
                    a = mnr;
                }
            }
        }
        if (chg) flags[0] = 1;
        __syncthreads();
        if (!flags[0]) break;
        for (int x = tid; x < nRuns; x += 128) {
            u32 p = runPar[x];
            runPar[x] = runPar[p];
        }
        __syncthreads();
    }

    for (int x = tid; x < nRuns; x += 128)
        if ((int)runPar[x] == x) labIdRun[x] = (unsigned short)atomicAdd(&flags[1], 1);
    __syncthreads();

    for (int j = 0; j < 8; ++j) {
        int i = tid + 128 * j;
        int r = i >> 5, c = i & 31;
        u32 fr = fgL[r];
        short s = 0;
        if ((fr >> c) & 1u) {
            u32 Sr = fr & ~(fr << 1);
            int x = (int)baseL[r] + __popc(Sr & ((2u << c) - 1u)) - 1;
            for (;;) { int p = (int)runPar[x]; if (p == x) break; x = p; }
            s = (short)((int)labIdRun[x] + 1);
        }
        seg[i] = s;
    }

    // ---- edge costs ----
    for (int e = tid; e < NEDGE; e += 128) {
        int a, b2; edgeAB(e, a, b2);
        costs[e] = predL[a] + predL[b2];
        gtcL[e]  = (unsigned char)(tgtL[a] + tgtL[b2]);
    }
    __syncthreads();
    // ======== no block barriers below this line: waves fully decoupled ========

    const int ph = wv;                 // 0 = neg, 1 = pos
    u32*   Ks_   = Ks[ph];
    short* par_  = par[ph];
    u64*   root_ = root[ph];
    u32*   pool_ = poolS[ph];
    short* H_    = H[ph];
    u32*   Q_    = Q[ph];
    float* Qw_   = Qw[ph];
    u32*   claim_= (u32*)Qw[ph];       // claim array during drain (Qw dead until replay)

    // ---- register-resident bitonic sort of 2048 u64 keys ----
    u64 sk[32];
    #pragma unroll
    for (int r = 0; r < 32; ++r) {
        int e = lane * 32 + r;
        u64 kv = ~0ULL;
        if (e < NEDGE) {
            float cv = costs[e];
            int g = gtcL[e];
            if (ph == 0) { if (g > 20) cv = 20.0f; }
            else         { if (g < 10) cv = 0.0f; }
            kv = (((u64)(~__float_as_uint(cv))) << 32) | (u32)e;
        }
        sk[r] = kv;
    }
    #pragma unroll
    for (int kk2 = 2; kk2 <= 32; kk2 <<= 1) {
        #pragma unroll
        for (int j = kk2 >> 1; j > 0; j >>= 1) {
            #pragma unroll
            for (int r = 0; r < 32; ++r) {
                if ((r & j) == 0) {
                    bool up = (kk2 == 32) ? ((lane & 1) == 0) : ((r & kk2) == 0);
                    CE(sk[r], sk[r | j], up);
                }
            }
        }
    }
    #pragma unroll
    for (int kk2 = 64; kk2 <= 2048; kk2 <<= 1) {
        const bool up = ((lane & (kk2 >> 5)) == 0);
        #pragma unroll
        for (int j = kk2 >> 1; j >= 32; j >>= 1) {
            const int xm = j >> 5;
            const bool keepmin = (((lane & xm) == 0) == up);
            #pragma unroll
            for (int r = 0; r < 32; ++r) { CEX(sk[r], xm, keepmin); }
        }
        #pragma unroll
        for (int j = 16; j > 0; j >>= 1) {
            #pragma unroll
            for (int r = 0; r < 32; ++r) {
                if ((r & j) == 0) { CE(sk[r], sk[r | j], up); }
            }
        }
    }
    #pragma unroll
    for (int r = 0; r < 32; r += 4) {
        uint4 v4;
        v4.x = (u32)sk[r]; v4.y = (u32)sk[r+1]; v4.z = (u32)sk[r+2]; v4.w = (u32)sk[r+3];
        *(uint4*)&Ks_[lane * 32 + r] = v4;
    }

    // ---- union-find init; labeled pixel i starts as INLINE singleton ----
    for (int i = lane; i < NPIX; i += 64) {
        short s2 = seg[i];
        par_[i] = (short)(i | (s2 ? 0x8000 : 0));
        root_[i] = s2 ? ((1ull << 62) | ((u32)(unsigned short)s2 << 16) | 1u) : 0ull;
        H_[i] = 0;
        claim_[i] = ~0u;
    }
    if (lane == 0) H_[NPIX] = 0;
    __builtin_amdgcn_wave_barrier();

    // ---- Kruskal drain: claim-batched parallel merges (unchanged) ----
    int qn = 0;
    u32 rnd = 1;
    const u64 ltm = (1ull << lane) - 1;
    int curE = (int)Ks_[lane];
    for (int g2 = 0; g2 < NGRP; ++g2) {
        int nextE = (g2 + 1 < NGRP) ? (int)Ks_[(g2 + 1) * 64 + lane] : 0;
        const int myE = curE;
        int ea, eb2; edgeAB(myE, ea, eb2);
        int ra = ea, rb = eb2;
        int laA, laB;
        for (;;) {
            int va = (int)(unsigned short)par_[ra];
            int vb = (int)(unsigned short)par_[rb];
            int pa = va & 0x3FF, pb = vb & 0x3FF;
            bool fa = (pa != ra), fb = (pb != rb);
            if (!fa && !fb) { laA = va >> 15; laB = vb >> 15; break; }
            int ga = (int)(unsigned short)par_[pa];
            int gb = (int)(unsigned short)par_[pb];
            if (fa) { par_[ra] = (short)ga; ra = ga & 0x3FF; }
            if (fb) { par_[rb] = (short)gb; rb = gb & 0x3FF; }
        }
        bool alive = (ra != rb);

        for (;;) {
            if (!__ballot(alive)) break;
            const bool av = alive;
            const u32 tag = ((0x03FFFFFFu - rnd) << 6) | (u32)lane;
            ++rnd;
            int mn = ra < rb ? ra : rb;
            int mx = ra < rb ? rb : ra;
            int winner = (laA == laB) ? mn : (laA ? ra : rb);
            int loser  = (laA == laB) ? mx : (laA ? rb : ra);
            bool wgt = (laA & laB) != 0;
            if (av)        atomicMin(&claim_[loser],  tag);
            if (av && wgt) atomicMin(&claim_[winner], tag);
            bool sel = false;
            if (av) {
                u32 cl = claim_[loser];
                u32 cw = wgt ? claim_[winner] : tag;
                sel = (cl == tag) && (cw == tag);
            }
            u64 wm = __ballot(sel && wgt);
            if (sel && wgt) Q_[qn + __popcll(wm & ltm)] =
                (u32)myE | ((u32)mn << 11) | ((u32)mx << 21);
            qn += (int)__popcll(wm);
            if (sel) par_[loser] = (short)winner;
            if (av) {
                for (;;) {
                    int va = (int)(unsigned short)par_[ra];
                    int vb = (int)(unsigned short)par_[rb];
                    int pa = va & 0x3FF, pb = vb & 0x3FF;
                    bool fa = (pa != ra), fb = (pb != rb);
                    if (!fa && !fb) { laA = va >> 15; laB = vb >> 15; break; }
                    int ga = (int)(unsigned short)par_[pa];
                    int gb = (int)(unsigned short)par_[pb];
                    if (fa) { par_[ra] = (short)ga; ra = ga & 0x3FF; }
                    if (fb) { par_[rb] = (short)gb; rb = gb & 0x3FF; }
                }
                alive = !sel && (ra != rb);
            }
        }
        curE = nextE;
        __builtin_amdgcn_wave_barrier();
    }

    // ---- replay with inline roots + software-pipelined prefetch ----
    u32 bump = NPIX;
    u32 halfEnd = NPIX + HFS;
    int curHalf = 0;

    auto do_gc = [&]() {           // compact POOL-BACKED live sets only
        u32 tgt = (curHalf == 0) ? (u32)(NPIX + HFS) : (u32)NPIX;
        u32 nb = tgt;
        for (int c = 0; c < 16; ++c) {
            int i0 = c * 64 + lane;
            u64 Ri = root_[i0];
            bool live = (Ri != 0) && ((Ri >> 62) == 0);
            u64 rbm = __ballot(live);
            while (rbm) {
                int j = __ffsll(rbm) - 1; rbm &= rbm - 1;
                int r = c * 64 + j;
                u64 R = root_[r];
                int len = R_LEN(R);
                int off = R_OFF(R);
                for (int t = lane; t < len; t += 64) {
                    u32 v2 = pool_[off + t];
                    pool_[nb + t] = v2;
                }
                __builtin_amdgcn_wave_barrier();
                if (lane == 0) root_[r] = packRoot(R_SL(R), (int)nb, len, len);
                nb += (u32)len;
            }
        }
        bump = nb;
        halfEnd = tgt + HFS;
        curHalf ^= 1;
    };

    u32 rec = 0; u64 RA = 0, RB = 0;
    if (qn > 0) {
        rec = Q_[0];
        int A0 = (int)((rec >> 11) & 0x3FF), B0 = (int)((rec >> 21) & 0x3FF);
        RA = root_[A0]; RB = root_[B0];
    }
    for (int q = 0; q < qn; ++q) {
        const int A = (int)((rec >> 11) & 0x3FF);
        const int B = (int)((rec >> 21) & 0x3FF);
        int tA = (int)(RA >> 62), tB = (int)(RB >> 62);
        int same, sLa, sLb;
        u64 newR;

        if (tA == 1 && tB == 1) {
            // fast path: two inline singleton-label sets
            u32 pa = (u32)RA & EMASK, pb = (u32)RB & EMASK;
            int ca = (int)(pa & 0xFFFF), cb = (int)(pb & 0xFFFF);
            sLa = ca; sLb = cb;
            if ((pa >> 16) == (pb >> 16)) {
                same = ca * cb;
                newR = (1ull << 62) | (u64)(pa + (u32)cb);
            } else {
                same = 0;
                newR = (2ull << 62) | ((u64)pb << 26) | pa;
            }
        } else {
            int lenA = tA ? tA : R_LEN(RA);
            int lenB = tB ? tB : R_LEN(RB);
            if (bump + (u32)(lenA + lenB + 8) > halfEnd) {
                do_gc();
                RA = root_[A]; RB = root_[B];
                tA = (int)(RA >> 62); tB = (int)(RB >> 62);
                lenA = tA ? tA : R_LEN(RA);
                lenB = tB ? tB : R_LEN(RB);
            }
            int offA = 0, capA = 0, offB = 0, capB = 0;
            if (tA == 0) { sLa = R_SL(RA); offA = R_OFF(RA); capA = R_CAP(RA); }
            else {
                u32 a0 = (u32)RA & EMASK, a1 = (u32)(RA >> 26) & EMASK;
                sLa = (int)(a0 & 0xFFFF) + ((tA == 2) ? (int)(a1 & 0xFFFF) : 0);
            }
            if (tB == 0) { sLb = R_SL(RB); offB = R_OFF(RB); capB = R_CAP(RB); }
            else {
                u32 b0 = (u32)RB & EMASK, b1 = (u32)(RB >> 26) & EMASK;
                sLb = (int)(b0 & 0xFFFF) + ((tB == 2) ? (int)(b1 & 0xFFFF) : 0);
            }
            // materialize lists into lanes when len<=64
            u32 eA = 0, eB = 0;
            if (lenA <= 64) {
                if (tA == 0) { if (lane < lenA) eA = pool_[offA + lane]; }
                else {
                    u32 a0 = (u32)RA & EMASK, a1 = (u32)(RA >> 26) & EMASK;
                    eA = (lane == 0) ? a0 : ((lane == 1 && tA == 2) ? a1 : 0);
                }
            }
            if (lenB <= 64) {
                if (tB == 0) { if (lane < lenB) eB = pool_[offB + lane]; }
                else {
                    u32 b0 = (u32)RB & EMASK, b1 = (u32)(RB >> 26) & EMASK;
                    eB = (lane == 0) ? b0 : ((lane == 1 && tB == 2) ? b1 : 0);
                }
            }
            // small/large select
            u32 eS, eL; int lenS, lenL, offS, offL, capL, tS, tL;
            if (lenA <= lenB) { eS=eA; lenS=lenA; offS=offA; tS=tA; eL=eB; lenL=lenB; offL=offB; capL=capB; tL=tB; }
            else              { eS=eB; lenS=lenB; offS=offB; tS=tB; eL=eA; lenL=lenA; offL=offA; capL=capA; tL=tA; }
            int dOff, dLen, dCap;
            same = 0;

            if (lenS + lenL <= 64) {
                // register path
                dLen = lenL;
                for (int t = 0; t < lenS; ++t) {
                    u32 xs = (u32)rdl((int)eS, t);
                    bool match = (lane < lenL) && ((eL >> 16) == (xs >> 16));
                    u64 mb = __ballot(match);
                    if (mb) {
                        int ml = __ffsll(mb) - 1;
                        same += (int)(xs & 0xFFFF) * ((int)rdl((int)eL, ml) & 0xFFFF);
                        if (match) eL += (xs & 0xFFFF);
                    } else {
                        if (lane == dLen) eL = xs;
                        dLen++;
                    }
                }
                if (dLen <= 2) {
                    u32 m0 = (u32)rdl((int)eL, 0) & EMASK;
                    u32 m1 = (dLen > 1) ? ((u32)rdl((int)eL, 1) & EMASK) : 0u;
                    newR = ((u64)(u32)dLen << 62) | ((u64)m1 << 26) | m0;
                } else {
                    if (tL == 0 && dLen <= capL) { dOff = offL; dCap = capL; }
                    else { dOff = (int)bump; dCap = (dLen + 3) & ~3; bump += (u32)dCap; }
                    if (lane < dLen) pool_[dOff + lane] = eL;
                    newR = packRoot(sLa + sLb, dOff, dLen, dCap);
                }
            } else {
                // slow path: large side is pool; histogram in H_
                dOff = (int)bump;
                dCap = (lenL + lenS + 4) & ~3; bump += (u32)dCap;
                if (lenS <= 64) {
                    if (lane < lenS) H_[eS >> 16] = (short)(eS & 0xFFFF);
                } else {
                    for (int j = lane; j < lenS; j += 64) {
                        u32 es = pool_[offS + j];
                        H_[es >> 16] = (short)(es & 0xFFFF);
                    }
                }
                __builtin_amdgcn_wave_barrier();
                int sp = 0;
                for (int j = lane; j < lenL; j += 64) {
                    u32 el = pool_[offL + j];
                    int h = (int)H_[el >> 16];
                    sp += h * (int)(el & 0xFFFF);
                    pool_[dOff + j] = el + (u32)h;
                    if (h) H_[el >> 16] = 0;
                }
                same = wredi(sp);
                __builtin_amdgcn_wave_barrier();
                int baseU = 0;
                if (lenS <= 64) {
                    bool un = (lane < lenS) && (H_[eS >> 16] != 0);
                    u64 ub = __ballot(un);
                    if (un) {
                        int pos = __popcll(ub & ltm);
                        pool_[dOff + lenL + pos] = eS;
                        H_[eS >> 16] = 0;
                    }
                    baseU = (int)__popcll(ub);
                } else {
                    for (int j0 = 0; j0 < lenS; j0 += 64) {
                        int j = j0 + lane;
                        bool un = false; u32 es = 0;
                        if (j < lenS) { es = pool_[offS + j]; un = (H_[es >> 16] != 0); }
                        u64 ub = __ballot(un);
                        if (un) {
                            int pos = __popcll(ub & ltm);
                            pool_[dOff + lenL + baseU + pos] = es;
                            H_[es >> 16] = 0;
                        }
                        baseU += (int)__popcll(ub);
                    }
                }
                dLen = lenL + baseU;
                newR = packRoot(sLa + sLb, dOff, dLen, dCap);
            }
        }

        float w = (float)(ph ? same : (sLa * sLb - same));

        // prefetch next record + roots BEFORE this merge's root writes
        u32 recN = 0; int An = -1, Bn = -1; u64 RAn = 0, RBn = 0;
        if (q + 1 < qn) {
            recN = Q_[q + 1];
            An = (int)((recN >> 11) & 0x3FF);
            Bn = (int)((recN >> 21) & 0x3FF);
            RAn = root_[An]; RBn = root_[Bn];
        }
        if (lane == 0) {
            Qw_[q] = w;
            root_[A] = newR;
            root_[B] = 0;
        }
        __builtin_amdgcn_wave_barrier();
        // patch prefetched roots (dead roots never reappear; only A can)
        if (An == A) RAn = newR;
        if (Bn == A) RBn = newR;
        rec = recN; RA = RAn; RB = RBn;
    }

    // ---- epilogue per wave ----
    float s_loc = 0.0f;
    for (int q = lane; q < qn; q += 64) s_loc += Qw_[q];
    const float sn = wredf(s_loc);

    const float scale = ph ? lrp_p[0] : lr_p[0];
    float acc = 0.0f;
    for (int q = lane; q < qn; q += 64) {
        float wv2 = Qw_[q];
        if (wv2 == 0.0f) continue;
        if (sn > 0.0f) wv2 /= sn;
        int me = (int)(Q_[q] & 0x7FF);
        int g = gtcL[me];
        bool zero = ph ? (g < 20) : (g >= 10);
        if (zero) continue;
        int a2, b2; edgeAB(me, a2, b2);
        float pa = predL[a2], pb = predL[b2];
        float fa2, fb2;
        if (ph == 0) { fa2 = pa * pa; fb2 = pb * pb; }
        else { float qa = 20.0f - pa, qb = 20.0f - pb; fa2 = qa * qa; fb2 = qb * qb; }
        acc += scale * wv2 * (fa2 + fb2);
    }
    acc = wredf(acc);
    if (lane == 0) atomicAdd(out, acc);
}

__global__ void zero_out_kernel(float* o)
{
    if (threadIdx.x == 0 && blockIdx.x == 0) o[0] = 0.0f;
}

extern "C" void kernel_launch(void* const* d_in, const int* in_sizes, int n_in,
                              void* d_out, int out_size, void* d_ws, size_t ws_size,
                              hipStream_t stream)
{
    const float* pred   = (const float*)d_in[0];
    const float* target = (const float*)d_in[1];
    const float* lr     = (const float*)d_in[2];
    const float* lrp    = (const float*)d_in[3];
    float* out = (float*)d_out;

    zero_out_kernel<<<1, 64, 0, stream>>>(out);
    malis_kernel<<<128, 128, 0, stream>>>(pred, target, lr, lrp, out);
}

// Round 5
// 322.371 us; speedup vs baseline: 1.3713x; 1.0459x over previous
//
#include <hip/hip_runtime.h>
#include <cstdint>

#define NPIX  1024
#define NH    992
#define NEDGE 1984
#define NSORT 2048
#define NGRP  31
#define HFS   4300
#define POOLN (NPIX + 2*HFS)   // 9624 u32 entries per phase

typedef unsigned long long u64;
typedef unsigned int u32;

// ---- root_ encoding ----
// 0 == dead/unlabeled.
// type = bits[62,64): 0 = pool-backed, 1 = inline x1, 2 = inline x2.
// pool-backed: sL[0,11) | off[11,25) | len[25,36) | cap[36,47)
// inline: entry k at bits[26k, 26k+26), entry = lab<<16 | cnt (lab<=1023, cnt<=1024)
static __device__ __forceinline__ u64 packRoot(int sL,int off,int len,int cap){
    return (u64)(u32)(sL & 0x7FF) | ((u64)(u32)(off & 0x3FFF) << 11) |
           ((u64)(u32)(len & 0x7FF) << 25) | ((u64)(u32)(cap & 0x7FF) << 36);
}
#define R_SL(R)  ((int)((R) & 0x7FF))
#define R_OFF(R) ((int)(((R)>>11) & 0x3FFF))
#define R_LEN(R) ((int)(((R)>>25) & 0x7FF))
#define R_CAP(R) ((int)(((R)>>36) & 0x7FF))
#define EMASK 0x3FFFFFFu

static __device__ __forceinline__ int rdl(int v, int l){ return __builtin_amdgcn_readlane(v, l); }

static __device__ __forceinline__ u64 sxor64(u64 v, int m){
    u32 lo = (u32)__shfl_xor((int)(v & 0xFFFFFFFFull), m, 64);
    u32 hi = (u32)__shfl_xor((int)(v >> 32), m, 64);
    return ((u64)hi << 32) | lo;
}

// edge id -> endpoints (reference order: 992 horizontal then 992 vertical)
static __device__ __forceinline__ void edgeAB(int e, int &a, int &b){
    if (e < NH) { int r = (int)((unsigned)e / 31u); a = e + r; b = a + 1; }
    else        { a = e - NH; b = a + 32; }
}

// in-register compare-exchange: x at lower global index
#define CE(x, y, up) { u64 _a=(x), _b=(y); bool _lt=(_a<_b); \
    u64 _mn=_lt?_a:_b, _mx=_lt?_b:_a; (x)=(up)?_mn:_mx; (y)=(up)?_mx:_mn; }
// cross-lane compare-exchange via shfl_xor
#define CEX(x, xm, keepmin) { u64 _p=sxor64((x),(xm)); bool _lt=((x)<_p); \
    u64 _mn=_lt?(x):_p, _mx=_lt?_p:(x); (x)=(keepmin)?_mn:_mx; }

static __device__ __forceinline__ int wredi(int v){
    #pragma unroll
    for (int o = 32; o > 0; o >>= 1) v += __shfl_xor(v, o, 64);
    return v;
}
static __device__ __forceinline__ float wredf(float v){
    #pragma unroll
    for (int o = 32; o > 0; o >>= 1) v += __shfl_xor(v, o, 64);
    return v;
}

__global__ __launch_bounds__(128) void malis_kernel(
    const float* __restrict__ pred,
    const float* __restrict__ target,
    const float* __restrict__ lr_p,
    const float* __restrict__ lrp_p,
    float* __restrict__ out)
{
    const int tid  = threadIdx.x;
    const int lane = tid & 63;
    const int wv   = tid >> 6;        // wave 0: negative pass, wave 1: positive pass
    const int bid  = blockIdx.x;
    const int bb   = bid >> 6;
    const int win  = bid & 63;
    const int wy   = win >> 3, wx = win & 7;
    const int base = bb * 65536 + (wy * 32) * 256 + wx * 32;

    // ---- LDS (~153 KB; 1 block/CU) ----
    __shared__ __align__(16) u32 Ks[2][NSORT]; // sorted edge indices
    __shared__ u64   root[2][NPIX];
    __shared__ float predL[NPIX];
    __shared__ float costs[NEDGE];
    __shared__ u32   poolS[2][POOLN];       // label-count arrays {lab<<16|cnt}
    __shared__ unsigned short Q[2][NPIX];   // merge edge ids (epilogue)
    __shared__ float Qw[2][NPIX];           // merge weights
    __shared__ u32   claimS[2][NPIX];       // drain claim tags
    __shared__ short seg[NPIX];
    __shared__ short par[2][NPIX];          // parent[9:0] | labeledStatic<<15
    __shared__ short H[2][NPIX + 1];        // slow-path histogram
    __shared__ unsigned char tgtL[NPIX];
    __shared__ unsigned char gtcL[NEDGE];
    __shared__ u32   rowmaskL[32];
    __shared__ u32   fgL[32];
    __shared__ unsigned short baseL[33];
    __shared__ int   flags[2];

    // early scratch overlaid on poolS (dead until UF init)
    u32* runPar = (u32*)poolS;                                  // 512 u32
    unsigned short* labIdRun = (unsigned short*)(runPar + 512); // 512 u16

    // ---- load window; build (target==0) row bitmasks via ballot ----
    for (int j = 0; j < 8; ++j) {
        int i = tid + 128 * j;
        int r = i >> 5, c = i & 31;
        float pv = pred[base + r * 256 + c];
        float tv = target[base + r * 256 + c];
        predL[i] = pv;
        tgtL[i]  = (unsigned char)tv;
        u64 zb = __ballot(tv == 0.0f);
        if (lane == 0) {
            int rr = 4 * j + 2 * wv;
            rowmaskL[rr]     = (u32)zb;
            rowmaskL[rr + 1] = (u32)(zb >> 32);
        }
    }
    if (tid == 0) flags[1] = 0;
    for (int x = tid; x < 512; x += 128) runPar[x] = (u32)x;
    __syncthreads();

    // ---- dilate 5x in wave0 registers (lane r holds row-r mask) ----
    if (tid < 32) {
        u32 m = rowmaskL[tid];
        #pragma unroll
        for (int it = 0; it < 5; ++it) {
            u32 um = __shfl(m, (tid == 0) ? 0 : tid - 1, 64);
            if (tid == 0) um = 0;
            u32 dm = __shfl(m, (tid == 31) ? 31 : tid + 1, 64);
            if (tid == 31) dm = 0;
            m = m | (m << 1) | (m >> 1) | um | dm;
        }
        u32 f = ~m;
        fgL[tid] = f;
        int ns = __popc(f & ~(f << 1));
        int x = ns;
        #pragma unroll
        for (int off = 1; off < 32; off <<= 1) {
            int y = __shfl(x, (tid >= off) ? tid - off : 0, 64);
            if (tid >= off) x += y;
        }
        baseL[tid] = (unsigned short)(x - ns);
        if (tid == 31) baseL[32] = (unsigned short)x;
    }
    __syncthreads();
    const int nRuns = (int)baseL[32];

    // ---- CCL (8-conn) as union-find over row runs ----
    for (;;) {
        if (tid == 0) flags[0] = 0;
        __syncthreads();
        bool chg = false;
        for (int j = 0; j < 8; ++j) {
            int i = tid + 128 * j;
            int r = i >> 5, c = i & 31;
            if (r == 0) continue;
            u32 fr = fgL[r];
            if (!((fr >> c) & 1u)) continue;
            u32 fu = fgL[r - 1];
            u32 nb = fu & (u32)((7ull << c) >> 1);
            if (!nb) continue;
            u32 Sr = fr & ~(fr << 1);
            int a = (int)baseL[r] + __popc(Sr & ((2u << c) - 1u)) - 1;
            for (;;) { int p = (int)runPar[a]; if (p == a) break; a = p; }
            u32 Su = fu & ~(fu << 1);
            int bu = (int)baseL[r - 1];
            while (nb) {
                int cc = __ffs((int)nb) - 1; nb &= nb - 1;
                int b = bu + __popc(Su & ((2u << cc) - 1u)) - 1;
                for (;;) { int p = (int)runPar[b]; if (p == b) break; b = p; }
                if (a != b) {
                    int mnr = a < b ? a : b;
                    int mxr = a ^ b ^ mnr;
                    atomicMin(&runPar[mxr], (u32)mnr);
                    chg = true;
                    a = mnr;
                }
            }
        }
        if (chg) flags[0] = 1;
        __syncthreads();
        if (!flags[0]) break;
        for (int x = tid; x < nRuns; x += 128) {
            u32 p = runPar[x];
            runPar[x] = runPar[p];
        }
        __syncthreads();
    }

    for (int x = tid; x < nRuns; x += 128)
        if ((int)runPar[x] == x) labIdRun[x] = (unsigned short)atomicAdd(&flags[1], 1);
    __syncthreads();

    for (int j = 0; j < 8; ++j) {
        int i = tid + 128 * j;
        int r = i >> 5, c = i & 31;
        u32 fr = fgL[r];
        short s = 0;
        if ((fr >> c) & 1u) {
            u32 Sr = fr & ~(fr << 1);
            int x = (int)baseL[r] + __popc(Sr & ((2u << c) - 1u)) - 1;
            for (;;) { int p = (int)runPar[x]; if (p == x) break; x = p; }
            s = (short)((int)labIdRun[x] + 1);
        }
        seg[i] = s;
    }

    // ---- edge costs ----
    for (int e = tid; e < NEDGE; e += 128) {
        int a, b2; edgeAB(e, a, b2);
        costs[e] = predL[a] + predL[b2];
        gtcL[e]  = (unsigned char)(tgtL[a] + tgtL[b2]);
    }
    __syncthreads();
    // ======== no block barriers below this line: waves fully decoupled ========

    const int ph = wv;                 // 0 = neg, 1 = pos
    u32*   Ks_   = Ks[ph];
    short* par_  = par[ph];
    u64*   root_ = root[ph];
    u32*   pool_ = poolS[ph];
    short* H_    = H[ph];
    unsigned short* Q_ = Q[ph];
    float* Qw_   = Qw[ph];
    u32*   claim_= claimS[ph];

    // ---- register-resident bitonic sort of 2048 u64 keys ----
    u64 sk[32];
    #pragma unroll
    for (int r = 0; r < 32; ++r) {
        int e = lane * 32 + r;
        u64 kv = ~0ULL;
        if (e < NEDGE) {
            float cv = costs[e];
            int g = gtcL[e];
            if (ph == 0) { if (g > 20) cv = 20.0f; }
            else         { if (g < 10) cv = 0.0f; }
            kv = (((u64)(~__float_as_uint(cv))) << 32) | (u32)e;
        }
        sk[r] = kv;
    }
    #pragma unroll
    for (int kk2 = 2; kk2 <= 32; kk2 <<= 1) {
        #pragma unroll
        for (int j = kk2 >> 1; j > 0; j >>= 1) {
            #pragma unroll
            for (int r = 0; r < 32; ++r) {
                if ((r & j) == 0) {
                    bool up = (kk2 == 32) ? ((lane & 1) == 0) : ((r & kk2) == 0);
                    CE(sk[r], sk[r | j], up);
                }
            }
        }
    }
    #pragma unroll
    for (int kk2 = 64; kk2 <= 2048; kk2 <<= 1) {
        const bool up = ((lane & (kk2 >> 5)) == 0);
        #pragma unroll
        for (int j = kk2 >> 1; j >= 32; j >>= 1) {
            const int xm = j >> 5;
            const bool keepmin = (((lane & xm) == 0) == up);
            #pragma unroll
            for (int r = 0; r < 32; ++r) { CEX(sk[r], xm, keepmin); }
        }
        #pragma unroll
        for (int j = 16; j > 0; j >>= 1) {
            #pragma unroll
            for (int r = 0; r < 32; ++r) {
                if ((r & j) == 0) { CE(sk[r], sk[r | j], up); }
            }
        }
    }
    #pragma unroll
    for (int r = 0; r < 32; r += 4) {
        uint4 v4;
        v4.x = (u32)sk[r]; v4.y = (u32)sk[r+1]; v4.z = (u32)sk[r+2]; v4.w = (u32)sk[r+3];
        *(uint4*)&Ks_[lane * 32 + r] = v4;
    }

    // ---- union-find init; labeled pixel i starts as INLINE singleton ----
    for (int i = lane; i < NPIX; i += 64) {
        short s2 = seg[i];
        par_[i] = (short)(i | (s2 ? 0x8000 : 0));
        root_[i] = s2 ? ((1ull << 62) | ((u32)(unsigned short)s2 << 16) | 1u) : 0ull;
        H_[i] = 0;
        claim_[i] = ~0u;
    }
    if (lane == 0) H_[NPIX] = 0;
    __builtin_amdgcn_wave_barrier();

    // ---- pool allocator + gc (used by rare >2-label merges) ----
    const u64 ltm = (1ull << lane) - 1;
    u32 bump = NPIX;
    u32 halfEnd = NPIX + HFS;
    int curHalf = 0;

    auto do_gc = [&]() {           // compact POOL-BACKED live sets only
        u32 tgt = (curHalf == 0) ? (u32)(NPIX + HFS) : (u32)NPIX;
        u32 nb = tgt;
        for (int c = 0; c < 16; ++c) {
            int i0 = c * 64 + lane;
            u64 Ri = root_[i0];
            bool live = (Ri != 0) && ((Ri >> 62) == 0);
            u64 rbm = __ballot(live);
            while (rbm) {
                int j = __ffsll(rbm) - 1; rbm &= rbm - 1;
                int r = c * 64 + j;
                u64 R = root_[r];
                int len = R_LEN(R);
                int off = R_OFF(R);
                for (int t = lane; t < len; t += 64) {
                    u32 v2 = pool_[off + t];
                    pool_[nb + t] = v2;
                }
                __builtin_amdgcn_wave_barrier();
                if (lane == 0) root_[r] = packRoot(R_SL(R), (int)nb, len, len);
                nb += (u32)len;
            }
        }
        bump = nb;
        halfEnd = tgt + HFS;
        curHalf ^= 1;
    };

    // ---- Kruskal drain with FUSED merge accounting ----
    // Claim-winning weighted lanes own BOTH roots exclusively -> per-lane
    // inline merge (<=2 distinct labels) right in the round; rare overflow
    // (>2 labels) or pool-backed merges run wave-wide immediately after.
    int qn = 0;
    u32 rnd = 1;
    int curE = (int)Ks_[lane];
    for (int g2 = 0; g2 < NGRP; ++g2) {
        int nextE = (g2 + 1 < NGRP) ? (int)Ks_[(g2 + 1) * 64 + lane] : 0;
        const int myE = curE;
        int ea, eb2; edgeAB(myE, ea, eb2);
        int ra = ea, rb = eb2;
        int laA, laB;
        for (;;) {
            int va = (int)(unsigned short)par_[ra];
            int vb = (int)(unsigned short)par_[rb];
            int pa = va & 0x3FF, pb = vb & 0x3FF;
            bool fa = (pa != ra), fb = (pb != rb);
            if (!fa && !fb) { laA = va >> 15; laB = vb >> 15; break; }
            int ga = (int)(unsigned short)par_[pa];
            int gb = (int)(unsigned short)par_[pb];
            if (fa) { par_[ra] = (short)ga; ra = ga & 0x3FF; }
            if (fb) { par_[rb] = (short)gb; rb = gb & 0x3FF; }
        }
        bool alive = (ra != rb);

        for (;;) {
            if (!__ballot(alive)) break;
            const bool av = alive;
            const u32 tag = ((0x03FFFFFFu - rnd) << 6) | (u32)lane;
            ++rnd;
            int mn = ra < rb ? ra : rb;
            int mx = ra ^ rb ^ mn;
            int winner = (laA == laB) ? mn : (laA ? ra : rb);
            int loser  = (laA == laB) ? mx : (laA ? rb : ra);
            bool wgt = (laA & laB) != 0;
            if (av)        atomicMin(&claim_[loser],  tag);
            if (av && wgt) atomicMin(&claim_[winner], tag);
            bool sel = false;
            if (av) {
                u32 cl = claim_[loser];
                u32 cw = wgt ? claim_[winner] : tag;
                sel = (cl == tag) && (cw == tag);
            }
            u64 wm = __ballot(sel && wgt);
            int qidx = qn + (int)__popcll(wm & ltm);
            qn += (int)__popcll(wm);
            if (sel) par_[loser] = (short)winner;

            // per-lane inline merge (winner = mn for weighted merges)
            bool needPool = false;
            if (sel && wgt) {
                u64 RW = root_[mn], RL = root_[mx];
                int tW = (int)(RW >> 62), tL2 = (int)(RL >> 62);
                if (tW != 0 && tL2 != 0) {
                    u32 a0 = (u32)RW & EMASK, a1 = (u32)(RW >> 26) & EMASK;
                    u32 b0 = (u32)RL & EMASK, b1 = (u32)(RL >> 26) & EMASK;
                    u32 la0 = a0 >> 16, la1 = a1 >> 16;
                    u32 lb0 = b0 >> 16, lb1 = b1 >> 16;
                    int ca0 = (int)(a0 & 0xFFFF), ca1 = (int)(a1 & 0xFFFF);
                    int cb0 = (int)(b0 & 0xFFFF), cb1 = (int)(b1 & 0xFFFF);
                    int sLa = ca0 + ((tW == 2) ? ca1 : 0);
                    int sLb = cb0 + ((tL2 == 2) ? cb1 : 0);
                    int same = 0;
                    if (lb0 == la0) same += ca0 * cb0;
                    else if (tW == 2 && lb0 == la1) same += ca1 * cb0;
                    if (tL2 == 2) {
                        if (lb1 == la0) same += ca0 * cb1;
                        else if (tW == 2 && lb1 == la1) same += ca1 * cb1;
                    }
                    u32 r0 = a0, r1 = (tW == 2) ? a1 : 0;
                    int n = tW; bool ovf = false;
                    if (lb0 == la0) r0 += (u32)cb0;
                    else if (tW == 2 && lb0 == la1) r1 += (u32)cb0;
                    else { if (n == 1) { r1 = b0; n = 2; } else ovf = true; }
                    if (tL2 == 2) {
                        if (lb1 == la0) r0 += (u32)cb1;
                        else if (tW == 2 && lb1 == la1) r1 += (u32)cb1;
                        else { if (n == 1) { r1 = b1; n = 2; } else ovf = true; }
                    }
                    if (!ovf) {
                        root_[mn] = ((u64)(u32)n << 62) | ((u64)r1 << 26) | r0;
                        root_[mx] = 0;
                        Qw_[qidx] = (float)(ph ? same : (sLa * sLb - same));
                        Q_[qidx]  = (unsigned short)myE;
                    } else needPool = true;
                } else needPool = true;
            }

            // wave-wide pool merges (rare: >2 distinct labels or pool-backed)
            u64 pm = __ballot(needPool);
            while (pm) {
                int f = __ffsll(pm) - 1; pm &= pm - 1;
                int A  = rdl(mn, f),  B  = rdl(mx, f);
                int e  = rdl(myE, f), qi = rdl(qidx, f);
                u64 RA = root_[A], RB = root_[B];
                int tA = (int)(RA >> 62), tB = (int)(RB >> 62);
                int lenA = tA ? tA : R_LEN(RA);
                int lenB = tB ? tB : R_LEN(RB);
                if (bump + (u32)(lenA + lenB + 8) > halfEnd) {
                    do_gc();
                    RA = root_[A]; RB = root_[B];
                    tA = (int)(RA >> 62); tB = (int)(RB >> 62);
                    lenA = tA ? tA : R_LEN(RA);
                    lenB = tB ? tB : R_LEN(RB);
                }
                int sLa, sLb;
                int offA = 0, capA = 0, offB = 0, capB = 0;
                if (tA == 0) { sLa = R_SL(RA); offA = R_OFF(RA); capA = R_CAP(RA); }
                else {
                    u32 a0 = (u32)RA & EMASK, a1 = (u32)(RA >> 26) & EMASK;
                    sLa = (int)(a0 & 0xFFFF) + ((tA == 2) ? (int)(a1 & 0xFFFF) : 0);
                }
                if (tB == 0) { sLb = R_SL(RB); offB = R_OFF(RB); capB = R_CAP(RB); }
                else {
                    u32 b0 = (u32)RB & EMASK, b1 = (u32)(RB >> 26) & EMASK;
                    sLb = (int)(b0 & 0xFFFF) + ((tB == 2) ? (int)(b1 & 0xFFFF) : 0);
                }
                u32 eA = 0, eB = 0;
                if (lenA <= 64) {
                    if (tA == 0) { if (lane < lenA) eA = pool_[offA + lane]; }
                    else {
                        u32 a0 = (u32)RA & EMASK, a1 = (u32)(RA >> 26) & EMASK;
                        eA = (lane == 0) ? a0 : ((lane == 1 && tA == 2) ? a1 : 0);
                    }
                }
                if (lenB <= 64) {
                    if (tB == 0) { if (lane < lenB) eB = pool_[offB + lane]; }
                    else {
                        u32 b0 = (u32)RB & EMASK, b1 = (u32)(RB >> 26) & EMASK;
                        eB = (lane == 0) ? b0 : ((lane == 1 && tB == 2) ? b1 : 0);
                    }
                }
                u32 eS, eL; int lenS, lenL, offS, offL, capL, tL;
                if (lenA <= lenB) { eS=eA; lenS=lenA; offS=offA; eL=eB; lenL=lenB; offL=offB; capL=capB; tL=tB; }
                else              { eS=eB; lenS=lenB; offS=offB; eL=eA; lenL=lenA; offL=offA; capL=capA; tL=tA; }
                int dOff, dLen, dCap;
                int same = 0;
                u64 newR;

                if (lenS + lenL <= 64) {
                    dLen = lenL;
                    for (int t = 0; t < lenS; ++t) {
                        u32 xs = (u32)rdl((int)eS, t);
                        bool match = (lane < lenL) && ((eL >> 16) == (xs >> 16));
                        u64 mb = __ballot(match);
                        if (mb) {
                            int ml = __ffsll(mb) - 1;
                            same += (int)(xs & 0xFFFF) * ((int)rdl((int)eL, ml) & 0xFFFF);
                            if (match) eL += (xs & 0xFFFF);
                        } else {
                            if (lane == dLen) eL = xs;
                            dLen++;
                        }
                    }
                    if (dLen <= 2) {
                        u32 m0 = (u32)rdl((int)eL, 0) & EMASK;
                        u32 m1 = (dLen > 1) ? ((u32)rdl((int)eL, 1) & EMASK) : 0u;
                        newR = ((u64)(u32)dLen << 62) | ((u64)m1 << 26) | m0;
                    } else {
                        if (tL == 0 && dLen <= capL) { dOff = offL; dCap = capL; }
                        else { dOff = (int)bump; dCap = (dLen + 3) & ~3; bump += (u32)dCap; }
                        if (lane < dLen) pool_[dOff + lane] = eL;
                        newR = packRoot(sLa + sLb, dOff, dLen, dCap);
                    }
                } else {
                    dOff = (int)bump;
                    dCap = (lenL + lenS + 4) & ~3; bump += (u32)dCap;
                    if (lenS <= 64) {
                        if (lane < lenS) H_[eS >> 16] = (short)(eS & 0xFFFF);
                    } else {
                        for (int j = lane; j < lenS; j += 64) {
                            u32 es = pool_[offS + j];
                            H_[es >> 16] = (short)(es & 0xFFFF);
                        }
                    }
                    __builtin_amdgcn_wave_barrier();
                    int sp = 0;
                    for (int j = lane; j < lenL; j += 64) {
                        u32 el = pool_[offL + j];
                        int h = (int)H_[el >> 16];
                        sp += h * (int)(el & 0xFFFF);
                        pool_[dOff + j] = el + (u32)h;
                        if (h) H_[el >> 16] = 0;
                    }
                    same = wredi(sp);
                    __builtin_amdgcn_wave_barrier();
                    int baseU = 0;
                    if (lenS <= 64) {
                        bool un = (lane < lenS) && (H_[eS >> 16] != 0);
                        u64 ub = __ballot(un);
                        if (un) {
                            int pos = __popcll(ub & ltm);
                            pool_[dOff + lenL + pos] = eS;
                            H_[eS >> 16] = 0;
                        }
                        baseU = (int)__popcll(ub);
                    } else {
                        for (int j0 = 0; j0 < lenS; j0 += 64) {
                            int j = j0 + lane;
                            bool un = false; u32 es = 0;
                            if (j < lenS) { es = pool_[offS + j]; un = (H_[es >> 16] != 0); }
                            u64 ub = __ballot(un);
                            if (un) {
                                int pos = __popcll(ub & ltm);
                                pool_[dOff + lenL + baseU + pos] = es;
                                H_[es >> 16] = 0;
                            }
                            baseU += (int)__popcll(ub);
                        }
                    }
                    dLen = lenL + baseU;
                    newR = packRoot(sLa + sLb, dOff, dLen, dCap);
                }
                if (lane == 0) {
                    Qw_[qi] = (float)(ph ? same : (sLa * sLb - same));
                    Q_[qi]  = (unsigned short)e;
                    root_[A] = newR;
                    root_[B] = 0;
                }
                __builtin_amdgcn_wave_barrier();
            }

            if (av) {
                for (;;) {
                    int va = (int)(unsigned short)par_[ra];
                    int vb = (int)(unsigned short)par_[rb];
                    int pa = va & 0x3FF, pb = vb & 0x3FF;
                    bool fa = (pa != ra), fb = (pb != rb);
                    if (!fa && !fb) { laA = va >> 15; laB = vb >> 15; break; }
                    int ga = (int)(unsigned short)par_[pa];
                    int gb = (int)(unsigned short)par_[pb];
                    if (fa) { par_[ra] = (short)ga; ra = ga & 0x3FF; }
                    if (fb) { par_[rb] = (short)gb; rb = gb & 0x3FF; }
                }
                alive = !sel && (ra != rb);
            }
        }
        curE = nextE;
        __builtin_amdgcn_wave_barrier();
    }

    // ---- epilogue per wave ----
    float s_loc = 0.0f;
    for (int q = lane; q < qn; q += 64) s_loc += Qw_[q];
    const float sn = wredf(s_loc);

    const float scale = ph ? lrp_p[0] : lr_p[0];
    float acc = 0.0f;
    for (int q = lane; q < qn; q += 64) {
        float wv2 = Qw_[q];
        if (wv2 == 0.0f) continue;
        if (sn > 0.0f) wv2 /= sn;
        int me = (int)Q_[q];
        int g = gtcL[me];
        bool zero = ph ? (g < 20) : (g >= 10);
        if (zero) continue;
        int a2, b2; edgeAB(me, a2, b2);
        float pa = predL[a2], pb = predL[b2];
        float fa2, fb2;
        if (ph == 0) { fa2 = pa * pa; fb2 = pb * pb; }
        else { float qa = 20.0f - pa, qb = 20.0f - pb; fa2 = qa * qa; fb2 = qb * qb; }
        acc += scale * wv2 * (fa2 + fb2);
    }
    acc = wredf(acc);
    if (lane == 0) atomicAdd(out, acc);
}

__global__ void zero_out_kernel(float* o)
{
    if (threadIdx.x == 0 && blockIdx.x == 0) o[0] = 0.0f;
}

extern "C" void kernel_launch(void* const* d_in, const int* in_sizes, int n_in,
                              void* d_out, int out_size, void* d_ws, size_t ws_size,
                              hipStream_t stream)
{
    const float* pred   = (const float*)d_in[0];
    const float* target = (const float*)d_in[1];
    const float* lr     = (const float*)d_in[2];
    const float* lrp    = (const float*)d_in[3];
    float* out = (float*)d_out;

    zero_out_kernel<<<1, 64, 0, stream>>>(out);
    malis_kernel<<<128, 128, 0, stream>>>(pred, target, lr, lrp, out);
}